// Round 1
// baseline (167.597 us; speedup 1.0000x reference)
//
#include <hip/hip_runtime.h>

// CausalSelfAttention: B=256 T=256 C=192 H=6 D=32, fp32 in/out, bf16 MFMA internal.
// 3 kernels: qkv-GEMM -> flash-attn per (b,h) -> out-GEMM.

using f32x4  = __attribute__((ext_vector_type(4))) float;
using bf16x8 = __attribute__((ext_vector_type(8))) __bf16;
using u16x8  = __attribute__((ext_vector_type(8))) unsigned short;

constexpr int Bn = 256;
constexpr int Tn = 256;
constexpr int Cn = 192;
constexpr int Hn = 6;
constexpr int Dn = 32;
constexpr int Mn = Bn * Tn;                 // 65536 tokens
// fold softmax scale and log2(e) into q: exp(x*scale) == exp2(x*scale*log2e)
constexpr float QSCALE = 0.2550533f;        // log2(e)/sqrt(32)

__device__ __forceinline__ unsigned short f2bf(float f) {
  unsigned int u = __builtin_bit_cast(unsigned int, f);
  u += 0x7fffu + ((u >> 16) & 1u);          // RNE
  return (unsigned short)(u >> 16);
}

__device__ __forceinline__ f32x4 mfma16x16x32(u16x8 a, u16x8 b, f32x4 c) {
  return __builtin_amdgcn_mfma_f32_16x16x32_bf16(
      __builtin_bit_cast(bf16x8, a), __builtin_bit_cast(bf16x8, b), c, 0, 0, 0);
}

// ---------------- kernel 1: qkv = x @ w_qkv^T, split+scale+store bf16 [B,H,T,D] ----
__global__ __launch_bounds__(256) void k_qkv(const float* __restrict__ x,
                                             const float* __restrict__ wqkv,
                                             unsigned short* __restrict__ qg,
                                             unsigned short* __restrict__ kg,
                                             unsigned short* __restrict__ vg) {
  __shared__ unsigned short As[64][200];   // 64 rows x 192 (+8 pad), bf16
  __shared__ unsigned short Bs[64][200];
  const int m0 = blockIdx.x * 64;
  const int n0 = blockIdx.y * 64;
  const int tid = threadIdx.x;

  // stage A (x rows) and B (w_qkv rows) fp32 -> bf16. 64*192/4 = 3072 float4, 12/thread.
#pragma unroll
  for (int it = 0; it < 12; ++it) {
    int f = tid + it * 256;
    int row = f / 48, c4 = (f % 48) * 4;
    float4 va = *reinterpret_cast<const float4*>(&x[(size_t)(m0 + row) * Cn + c4]);
    ushort4 ua; ua.x = f2bf(va.x); ua.y = f2bf(va.y); ua.z = f2bf(va.z); ua.w = f2bf(va.w);
    *reinterpret_cast<ushort4*>(&As[row][c4]) = ua;
    float4 vb = *reinterpret_cast<const float4*>(&wqkv[(size_t)(n0 + row) * Cn + c4]);
    ushort4 ub; ub.x = f2bf(vb.x); ub.y = f2bf(vb.y); ub.z = f2bf(vb.z); ub.w = f2bf(vb.w);
    *reinterpret_cast<ushort4*>(&Bs[row][c4]) = ub;
  }
  __syncthreads();

  const int wv = tid >> 6, lane = tid & 63, llo = lane & 15, lhi = lane >> 4;
  const int wm = (wv >> 1) * 32, wn = (wv & 1) * 32;
  f32x4 acc[2][2] = {};
#pragma unroll
  for (int ks = 0; ks < 6; ++ks) {
    u16x8 a[2], b[2];
#pragma unroll
    for (int i = 0; i < 2; ++i)
      a[i] = *reinterpret_cast<const u16x8*>(&As[wm + 16 * i + llo][ks * 32 + lhi * 8]);
#pragma unroll
    for (int j = 0; j < 2; ++j)
      b[j] = *reinterpret_cast<const u16x8*>(&Bs[wn + 16 * j + llo][ks * 32 + lhi * 8]);
#pragma unroll
    for (int i = 0; i < 2; ++i)
#pragma unroll
      for (int j = 0; j < 2; ++j)
        acc[i][j] = mfma16x16x32(a[i], b[j], acc[i][j]);
  }
  // epilogue: split into q/k/v [B,H,T,D] bf16, q pre-scaled
#pragma unroll
  for (int i = 0; i < 2; ++i)
#pragma unroll
    for (int j = 0; j < 2; ++j)
#pragma unroll
      for (int r = 0; r < 4; ++r) {
        int mg = m0 + wm + 16 * i + lhi * 4 + r;
        int ng = n0 + wn + 16 * j + llo;
        int s = ng / 192;
        int rem = ng - s * 192;
        int h = rem >> 5, d = rem & 31;
        int bb = mg >> 8, t = mg & 255;
        float val = acc[i][j][r];
        unsigned short* dst = (s == 0) ? qg : (s == 1) ? kg : vg;
        float sv = (s == 0) ? val * QSCALE : val;
        dst[((size_t)(bb * Hn + h) * Tn + t) * Dn + d] = f2bf(sv);
      }
}

// ---------------- kernel 2: flash attention per (b,h), causal -----------------------
__global__ __launch_bounds__(256) void k_attn(const unsigned short* __restrict__ qg,
                                              const unsigned short* __restrict__ kg,
                                              const unsigned short* __restrict__ vg,
                                              unsigned short* __restrict__ yg) {
  __shared__ unsigned short Ks[256][40];    // K rows, +8 pad
  __shared__ unsigned short Vt[32][264];    // V transposed [d][t], +8 pad
  __shared__ unsigned short Ps[4][64][72];  // per-wave P tile, +8 pad
  const int bh = blockIdx.x;
  const int b = bh / Hn, h = bh - b * Hn;
  const size_t base = (size_t)bh * Tn * Dn;
  const int tid = threadIdx.x;

  { // stage K (row-major) and V (transposed): one row per thread
    int row = tid;
    const unsigned short* kp = kg + base + (size_t)row * Dn;
    *reinterpret_cast<uint4*>(&Ks[row][0])  = *reinterpret_cast<const uint4*>(kp + 0);
    *reinterpret_cast<uint4*>(&Ks[row][8])  = *reinterpret_cast<const uint4*>(kp + 8);
    *reinterpret_cast<uint4*>(&Ks[row][16]) = *reinterpret_cast<const uint4*>(kp + 16);
    *reinterpret_cast<uint4*>(&Ks[row][24]) = *reinterpret_cast<const uint4*>(kp + 24);
    const unsigned short* vp = vg + base + (size_t)row * Dn;
    u16x8 v0 = *reinterpret_cast<const u16x8*>(vp + 0);
    u16x8 v1 = *reinterpret_cast<const u16x8*>(vp + 8);
    u16x8 v2 = *reinterpret_cast<const u16x8*>(vp + 16);
    u16x8 v3 = *reinterpret_cast<const u16x8*>(vp + 24);
#pragma unroll
    for (int e = 0; e < 8; ++e) {
      Vt[e][row]      = v0[e];
      Vt[8 + e][row]  = v1[e];
      Vt[16 + e][row] = v2[e];
      Vt[24 + e][row] = v3[e];
    }
  }
  __syncthreads();

  const int w = tid >> 6, lane = tid & 63, llo = lane & 15, lhi = lane >> 4;
  // Q fragments for this wave's 64 rows (already scaled by QSCALE in k1)
  u16x8 qf[4];
  const unsigned short* qp = qg + base + (size_t)w * 64 * Dn;
#pragma unroll
  for (int i = 0; i < 4; ++i)
    qf[i] = *reinterpret_cast<const u16x8*>(qp + (size_t)(16 * i + llo) * Dn + lhi * 8);

  f32x4 o[4][2] = {};
  float m_[4][4], l_[4][4];
#pragma unroll
  for (int qi = 0; qi < 4; ++qi)
#pragma unroll
    for (int r = 0; r < 4; ++r) { m_[qi][r] = -1e30f; l_[qi][r] = 0.f; }

  for (int kt = 0; kt <= w; ++kt) {          // causal: only tiles at/below diagonal
    f32x4 s[4][4] = {};
#pragma unroll
    for (int kj = 0; kj < 4; ++kj) {
      u16x8 kf = *reinterpret_cast<const u16x8*>(&Ks[kt * 64 + kj * 16 + llo][lhi * 8]);
#pragma unroll
      for (int qi = 0; qi < 4; ++qi)
        s[qi][kj] = mfma16x16x32(qf[qi], kf, s[qi][kj]);
    }
    if (kt == w) {                           // diagonal tile: mask k > q
#pragma unroll
      for (int qi = 0; qi < 4; ++qi)
#pragma unroll
        for (int kj = 0; kj < 4; ++kj)
#pragma unroll
          for (int r = 0; r < 4; ++r) {
            int qrow = 16 * qi + lhi * 4 + r;
            int kcol = 16 * kj + llo;
            if (kcol > qrow) s[qi][kj][r] = -1e30f;
          }
    }
    // online softmax (exp2 domain; scale folded into q)
#pragma unroll
    for (int qi = 0; qi < 4; ++qi) {
#pragma unroll
      for (int r = 0; r < 4; ++r) {
        float t0 = fmaxf(fmaxf(s[qi][0][r], s[qi][1][r]), fmaxf(s[qi][2][r], s[qi][3][r]));
        t0 = fmaxf(t0, __shfl_xor(t0, 1));
        t0 = fmaxf(t0, __shfl_xor(t0, 2));
        t0 = fmaxf(t0, __shfl_xor(t0, 4));
        t0 = fmaxf(t0, __shfl_xor(t0, 8));
        float mn = fmaxf(m_[qi][r], t0);
        float al = exp2f(m_[qi][r] - mn);
        float sum = 0.f;
#pragma unroll
        for (int kj = 0; kj < 4; ++kj) {
          float p = exp2f(s[qi][kj][r] - mn);
          s[qi][kj][r] = p;
          sum += p;
        }
        sum += __shfl_xor(sum, 1);
        sum += __shfl_xor(sum, 2);
        sum += __shfl_xor(sum, 4);
        sum += __shfl_xor(sum, 8);
        l_[qi][r] = l_[qi][r] * al + sum;
        m_[qi][r] = mn;
        o[qi][0][r] *= al;
        o[qi][1][r] *= al;
      }
    }
    // P -> LDS (bf16), layout [q_local][k_local]
#pragma unroll
    for (int qi = 0; qi < 4; ++qi)
#pragma unroll
      for (int kj = 0; kj < 4; ++kj)
#pragma unroll
        for (int r = 0; r < 4; ++r)
          Ps[w][16 * qi + lhi * 4 + r][16 * kj + llo] = f2bf(s[qi][kj][r]);
    asm volatile("s_waitcnt lgkmcnt(0)" ::: "memory");
    // PV: O += P @ V
#pragma unroll
    for (int ks = 0; ks < 2; ++ks) {
      u16x8 vf[2];
#pragma unroll
      for (int dj = 0; dj < 2; ++dj)
        vf[dj] = *reinterpret_cast<const u16x8*>(&Vt[16 * dj + llo][kt * 64 + ks * 32 + lhi * 8]);
#pragma unroll
      for (int qi = 0; qi < 4; ++qi) {
        u16x8 pf = *reinterpret_cast<const u16x8*>(&Ps[w][16 * qi + llo][ks * 32 + lhi * 8]);
#pragma unroll
        for (int dj = 0; dj < 2; ++dj)
          o[qi][dj] = mfma16x16x32(pf, vf[dj], o[qi][dj]);
      }
    }
  }
  // finalize: O /= l, store y as bf16 [B,T,H,D]  (C index = h*D+d)
#pragma unroll
  for (int qi = 0; qi < 4; ++qi)
#pragma unroll
    for (int r = 0; r < 4; ++r) {
      float inv = 1.0f / l_[qi][r];
      int t = w * 64 + 16 * qi + lhi * 4 + r;
      size_t yo = ((size_t)(b * Tn + t) * Hn + h) * Dn;
      yg[yo + llo]      = f2bf(o[qi][0][r] * inv);
      yg[yo + 16 + llo] = f2bf(o[qi][1][r] * inv);
    }
}

// ---------------- kernel 3: out = y @ w_out^T (fp32 out) ---------------------------
__global__ __launch_bounds__(256) void k_out(const unsigned short* __restrict__ yg,
                                             const float* __restrict__ wout,
                                             float* __restrict__ out) {
  __shared__ unsigned short As[64][200];
  __shared__ unsigned short Bs[64][200];
  const int m0 = blockIdx.x * 64;
  const int n0 = blockIdx.y * 64;
  const int tid = threadIdx.x;

#pragma unroll
  for (int it = 0; it < 6; ++it) {           // A: bf16 copy, 64*192/8 = 1536 chunks
    int f = tid + it * 256;
    int row = f / 24, c8 = (f % 24) * 8;
    *reinterpret_cast<uint4*>(&As[row][c8]) =
        *reinterpret_cast<const uint4*>(&yg[(size_t)(m0 + row) * Cn + c8]);
  }
#pragma unroll
  for (int it = 0; it < 12; ++it) {          // B: fp32 -> bf16
    int f = tid + it * 256;
    int row = f / 48, c4 = (f % 48) * 4;
    float4 vb = *reinterpret_cast<const float4*>(&wout[(size_t)(n0 + row) * Cn + c4]);
    ushort4 ub; ub.x = f2bf(vb.x); ub.y = f2bf(vb.y); ub.z = f2bf(vb.z); ub.w = f2bf(vb.w);
    *reinterpret_cast<ushort4*>(&Bs[row][c4]) = ub;
  }
  __syncthreads();

  const int wv = tid >> 6, lane = tid & 63, llo = lane & 15, lhi = lane >> 4;
  const int wm = (wv >> 1) * 32, wn = (wv & 1) * 32;
  f32x4 acc[2][2] = {};
#pragma unroll
  for (int ks = 0; ks < 6; ++ks) {
    u16x8 a[2], b[2];
#pragma unroll
    for (int i = 0; i < 2; ++i)
      a[i] = *reinterpret_cast<const u16x8*>(&As[wm + 16 * i + llo][ks * 32 + lhi * 8]);
#pragma unroll
    for (int j = 0; j < 2; ++j)
      b[j] = *reinterpret_cast<const u16x8*>(&Bs[wn + 16 * j + llo][ks * 32 + lhi * 8]);
#pragma unroll
    for (int i = 0; i < 2; ++i)
#pragma unroll
      for (int j = 0; j < 2; ++j)
        acc[i][j] = mfma16x16x32(a[i], b[j], acc[i][j]);
  }
#pragma unroll
  for (int i = 0; i < 2; ++i)
#pragma unroll
    for (int j = 0; j < 2; ++j)
#pragma unroll
      for (int r = 0; r < 4; ++r) {
        int mg = m0 + wm + 16 * i + lhi * 4 + r;
        int ng = n0 + wn + 16 * j + llo;
        out[(size_t)mg * Cn + ng] = acc[i][j][r];
      }
}

extern "C" void kernel_launch(void* const* d_in, const int* in_sizes, int n_in,
                              void* d_out, int out_size, void* d_ws, size_t ws_size,
                              hipStream_t stream) {
  const float* x    = (const float*)d_in[0];
  const float* wqkv = (const float*)d_in[1];
  const float* wout = (const float*)d_in[2];
  float* out = (float*)d_out;

  const size_t NE = (size_t)Mn * Cn;        // 12,582,912 elements per tensor
  unsigned short* q = (unsigned short*)d_ws;
  unsigned short* k = q + NE;
  unsigned short* v = k + NE;
  unsigned short* y = v + NE;               // total 4*NE*2B = 100.7 MB of ws

  k_qkv<<<dim3(Mn / 64, (3 * Cn) / 64), 256, 0, stream>>>(x, wqkv, q, k, v);
  k_attn<<<dim3(Bn * Hn), 256, 0, stream>>>(q, k, v, y);
  k_out<<<dim3(Mn / 64, Cn / 64), 256, 0, stream>>>(y, wout, out);
}

// Round 2
// 131.715 us; speedup vs baseline: 1.2724x; 1.2724x over previous
//
#include <hip/hip_runtime.h>

// CausalSelfAttention: B=256 T=256 C=192 H=6 D=32, fp32 in/out, bf16 MFMA internal.
// 3 kernels: qkv-GEMM -> flash-attn per (b,h) (swapped-QK^T, in-register softmax) -> out-GEMM.

using f32x4  = __attribute__((ext_vector_type(4))) float;
using bf16x8 = __attribute__((ext_vector_type(8))) __bf16;
using u16x8  = __attribute__((ext_vector_type(8))) unsigned short;
using i32x4  = __attribute__((ext_vector_type(4))) int;

constexpr int Bn = 256;
constexpr int Tn = 256;
constexpr int Cn = 192;
constexpr int Hn = 6;
constexpr int Dn = 32;
constexpr int Mn = Bn * Tn;                 // 65536 tokens
// fold softmax scale and log2(e) into q: exp(x*scale) == exp2(x*scale*log2e)
constexpr float QSCALE = 0.2550533f;        // log2(e)/sqrt(32)

__device__ __forceinline__ unsigned short f2bf(float f) {
  unsigned int u = __builtin_bit_cast(unsigned int, f);
  u += 0x7fffu + ((u >> 16) & 1u);          // RNE
  return (unsigned short)(u >> 16);
}

__device__ __forceinline__ unsigned int cvtpk(float lo, float hi) {
  unsigned int r;
  asm("v_cvt_pk_bf16_f32 %0, %1, %2" : "=v"(r) : "v"(lo), "v"(hi));
  return r;
}

__device__ __forceinline__ f32x4 mfma16x16x32(u16x8 a, u16x8 b, f32x4 c) {
  return __builtin_amdgcn_mfma_f32_16x16x32_bf16(
      __builtin_bit_cast(bf16x8, a), __builtin_bit_cast(bf16x8, b), c, 0, 0, 0);
}

// ---------------- kernel 1: qkv = x @ w_qkv^T, split+scale+store bf16 [B,H,T,D] ----
__global__ __launch_bounds__(256) void k_qkv(const float* __restrict__ x,
                                             const float* __restrict__ wqkv,
                                             unsigned short* __restrict__ qg,
                                             unsigned short* __restrict__ kg,
                                             unsigned short* __restrict__ vg) {
  __shared__ unsigned short As[64][200];   // 64 rows x 192 (+8 pad), bf16
  __shared__ unsigned short Bs[64][200];
  const int m0 = blockIdx.x * 64;
  const int n0 = blockIdx.y * 64;
  const int tid = threadIdx.x;

#pragma unroll
  for (int it = 0; it < 12; ++it) {
    int f = tid + it * 256;
    int row = f / 48, c4 = (f % 48) * 4;
    float4 va = *reinterpret_cast<const float4*>(&x[(size_t)(m0 + row) * Cn + c4]);
    ushort4 ua; ua.x = f2bf(va.x); ua.y = f2bf(va.y); ua.z = f2bf(va.z); ua.w = f2bf(va.w);
    *reinterpret_cast<ushort4*>(&As[row][c4]) = ua;
    float4 vb = *reinterpret_cast<const float4*>(&wqkv[(size_t)(n0 + row) * Cn + c4]);
    ushort4 ub; ub.x = f2bf(vb.x); ub.y = f2bf(vb.y); ub.z = f2bf(vb.z); ub.w = f2bf(vb.w);
    *reinterpret_cast<ushort4*>(&Bs[row][c4]) = ub;
  }
  __syncthreads();

  const int wv = tid >> 6, lane = tid & 63, llo = lane & 15, lhi = lane >> 4;
  const int wm = (wv >> 1) * 32, wn = (wv & 1) * 32;
  f32x4 acc[2][2] = {};
#pragma unroll
  for (int ks = 0; ks < 6; ++ks) {
    u16x8 a[2], b[2];
#pragma unroll
    for (int i = 0; i < 2; ++i)
      a[i] = *reinterpret_cast<const u16x8*>(&As[wm + 16 * i + llo][ks * 32 + lhi * 8]);
#pragma unroll
    for (int j = 0; j < 2; ++j)
      b[j] = *reinterpret_cast<const u16x8*>(&Bs[wn + 16 * j + llo][ks * 32 + lhi * 8]);
#pragma unroll
    for (int i = 0; i < 2; ++i)
#pragma unroll
      for (int j = 0; j < 2; ++j)
        acc[i][j] = mfma16x16x32(a[i], b[j], acc[i][j]);
  }
#pragma unroll
  for (int i = 0; i < 2; ++i)
#pragma unroll
    for (int j = 0; j < 2; ++j)
#pragma unroll
      for (int r = 0; r < 4; ++r) {
        int mg = m0 + wm + 16 * i + lhi * 4 + r;
        int ng = n0 + wn + 16 * j + llo;
        int s = ng / 192;
        int rem = ng - s * 192;
        int h = rem >> 5, d = rem & 31;
        int bb = mg >> 8, t = mg & 255;
        float val = acc[i][j][r];
        unsigned short* dst = (s == 0) ? qg : (s == 1) ? kg : vg;
        float sv = (s == 0) ? val * QSCALE : val;
        dst[((size_t)(bb * Hn + h) * Tn + t) * Dn + d] = f2bf(sv);
      }
}

// ---------------- kernel 2: flash attention per (b,h), causal, swapped-QK^T --------
// S^T = mfma(K,Q): lane(llo,lhi) holds S[q=16*qi+llo][k = kj*16+lhi*4+r] per qi.
// Softmax reduce over k is in-lane (16 vals) + shfl_xor(16,32) over lhi.
// P^T repacked to B-frag in-register (cvt_pk + ds_bpermute), O^T = V^T @ P^T.
__global__ __launch_bounds__(256, 3) void k_attn(const unsigned short* __restrict__ qg,
                                                 const unsigned short* __restrict__ kg,
                                                 const unsigned short* __restrict__ vg,
                                                 unsigned short* __restrict__ yg) {
  __shared__ unsigned short Ks[256][40];    // K rows, +8 pad
  __shared__ unsigned short Vt[32][264];    // V transposed [d][t], +8 pad
  const int bh = blockIdx.x;
  const int b = bh / Hn, h = bh - b * Hn;
  const size_t base = (size_t)bh * Tn * Dn;
  const int tid = threadIdx.x;

  { // stage K (row-major) and V (transposed): one row per thread
    int row = tid;
    const unsigned short* kp = kg + base + (size_t)row * Dn;
    *reinterpret_cast<uint4*>(&Ks[row][0])  = *reinterpret_cast<const uint4*>(kp + 0);
    *reinterpret_cast<uint4*>(&Ks[row][8])  = *reinterpret_cast<const uint4*>(kp + 8);
    *reinterpret_cast<uint4*>(&Ks[row][16]) = *reinterpret_cast<const uint4*>(kp + 16);
    *reinterpret_cast<uint4*>(&Ks[row][24]) = *reinterpret_cast<const uint4*>(kp + 24);
    const unsigned short* vp = vg + base + (size_t)row * Dn;
    u16x8 v0 = *reinterpret_cast<const u16x8*>(vp + 0);
    u16x8 v1 = *reinterpret_cast<const u16x8*>(vp + 8);
    u16x8 v2 = *reinterpret_cast<const u16x8*>(vp + 16);
    u16x8 v3 = *reinterpret_cast<const u16x8*>(vp + 24);
#pragma unroll
    for (int e = 0; e < 8; ++e) {
      Vt[e][row]      = v0[e];
      Vt[8 + e][row]  = v1[e];
      Vt[16 + e][row] = v2[e];
      Vt[24 + e][row] = v3[e];
    }
  }
  __syncthreads();

  const int w = tid >> 6, lane = tid & 63, llo = lane & 15, lhi = lane >> 4;
  // Q fragments: lane holds Q[q=16*qi+llo][d=lhi*8..+7]  (B-operand of S^T)
  u16x8 qf[4];
  const unsigned short* qp = qg + base + (size_t)w * 64 * Dn;
#pragma unroll
  for (int i = 0; i < 4; ++i)
    qf[i] = *reinterpret_cast<const u16x8*>(qp + (size_t)(16 * i + llo) * Dn + lhi * 8);

  f32x4 ot[2][4] = {};                      // O^T: [dj][qi], col=q=llo, row=d=lhi*4+r
  float m_[4], l_[4];
#pragma unroll
  for (int qi = 0; qi < 4; ++qi) { m_[qi] = -1e30f; l_[qi] = 0.f; }

  // ds_bpermute addresses for P^T repack (src lane = llo + 16*((lhi&1)*2 + (j>>1)))
  const int addr0 = (llo + ((lhi & 1) << 5)) << 2;   // j = 0,1
  const int addr1 = addr0 + 64;                      // j = 2,3

  for (int kt = 0; kt <= w; ++kt) {          // causal: only tiles at/below diagonal
    u16x8 kf[4];
#pragma unroll
    for (int kj = 0; kj < 4; ++kj)
      kf[kj] = *reinterpret_cast<const u16x8*>(&Ks[kt * 64 + kj * 16 + llo][lhi * 8]);
    u16x8 vtf[2][2];
#pragma unroll
    for (int ks = 0; ks < 2; ++ks)
#pragma unroll
      for (int dj = 0; dj < 2; ++dj)
        vtf[ks][dj] = *reinterpret_cast<const u16x8*>(&Vt[16 * dj + llo][kt * 64 + ks * 32 + lhi * 8]);

#pragma unroll
    for (int qi = 0; qi < 4; ++qi) {
      // S^T tile column: st[kj][r] = S[q=16qi+llo][k=kj*16+lhi*4+r]
      f32x4 st[4];
#pragma unroll
      for (int kj = 0; kj < 4; ++kj)
        st[kj] = mfma16x16x32(kf[kj], qf[qi], f32x4{});
      if (kt == w) {                         // diagonal tile: mask k > q
        int ql = 16 * qi + llo;
#pragma unroll
        for (int kj = 0; kj < 4; ++kj)
#pragma unroll
          for (int r = 0; r < 4; ++r) {
            int kl = kj * 16 + lhi * 4 + r;
            st[kj][r] = (kl > ql) ? -1e30f : st[kj][r];
          }
      }
      // online softmax: in-lane max/sum trees + 2 shfl over lhi
      float x0 = fmaxf(fmaxf(st[0][0], st[0][1]), fmaxf(st[0][2], st[0][3]));
      float x1 = fmaxf(fmaxf(st[1][0], st[1][1]), fmaxf(st[1][2], st[1][3]));
      float x2 = fmaxf(fmaxf(st[2][0], st[2][1]), fmaxf(st[2][2], st[2][3]));
      float x3 = fmaxf(fmaxf(st[3][0], st[3][1]), fmaxf(st[3][2], st[3][3]));
      float mx = fmaxf(fmaxf(x0, x1), fmaxf(x2, x3));
      mx = fmaxf(mx, __shfl_xor(mx, 16));
      mx = fmaxf(mx, __shfl_xor(mx, 32));
      float mn = fmaxf(m_[qi], mx);
      float al = exp2f(m_[qi] - mn);
      float sum = 0.f;
#pragma unroll
      for (int kj = 0; kj < 4; ++kj) {
        float p0 = exp2f(st[kj][0] - mn);
        float p1 = exp2f(st[kj][1] - mn);
        float p2 = exp2f(st[kj][2] - mn);
        float p3 = exp2f(st[kj][3] - mn);
        st[kj][0] = p0; st[kj][1] = p1; st[kj][2] = p2; st[kj][3] = p3;
        sum += (p0 + p1) + (p2 + p3);
      }
      sum += __shfl_xor(sum, 16);
      sum += __shfl_xor(sum, 32);
      l_[qi] = l_[qi] * al + sum;
      m_[qi] = mn;
#pragma unroll
      for (int dj = 0; dj < 2; ++dj)
#pragma unroll
        for (int r = 0; r < 4; ++r)
          ot[dj][qi][r] *= al;

      // pack P (bf16 pairs along k): pk0 = (r0,r1), pk1 = (r2,r3) per kj
      int pk0[4], pk1[4];
#pragma unroll
      for (int kj = 0; kj < 4; ++kj) {
        pk0[kj] = (int)cvtpk(st[kj][0], st[kj][1]);
        pk1[kj] = (int)cvtpk(st[kj][2], st[kj][3]);
      }
      // repack to B-frag (col=q=llo, k=ks*32+lhi*8+i) via ds_bpermute, then PV
#pragma unroll
      for (int ks = 0; ks < 2; ++ks) {
        i32x4 pw;
#pragma unroll
        for (int j = 0; j < 4; ++j) {
          int addr = (j < 2) ? addr0 : addr1;
          int slo = (j & 1) ? pk1[2 * ks]     : pk0[2 * ks];
          int shi = (j & 1) ? pk1[2 * ks + 1] : pk0[2 * ks + 1];
          int blo = __builtin_amdgcn_ds_bpermute(addr, slo);
          int bhi = __builtin_amdgcn_ds_bpermute(addr, shi);
          pw[j] = (lhi & 2) ? bhi : blo;
        }
        u16x8 pbv = __builtin_bit_cast(u16x8, pw);
#pragma unroll
        for (int dj = 0; dj < 2; ++dj)
          ot[dj][qi] = mfma16x16x32(vtf[ks][dj], pbv, ot[dj][qi]);
      }
    }
  }
  // finalize: O^T /= l (lane-local), store y bf16 [B,T,H,D]; lane's q=16qi+llo,
  // d = 16*dj + lhi*4 + r (4 consecutive d -> one 8B packed store)
#pragma unroll
  for (int qi = 0; qi < 4; ++qi) {
    float rl = 1.0f / l_[qi];
    int t = w * 64 + 16 * qi + llo;
    size_t yo = ((size_t)(b * Tn + t) * Hn + h) * Dn;
#pragma unroll
    for (int dj = 0; dj < 2; ++dj) {
      uint2 pkd;
      pkd.x = cvtpk(ot[dj][qi][0] * rl, ot[dj][qi][1] * rl);
      pkd.y = cvtpk(ot[dj][qi][2] * rl, ot[dj][qi][3] * rl);
      *reinterpret_cast<uint2*>(&yg[yo + 16 * dj + lhi * 4]) = pkd;
    }
  }
}

// ---------------- kernel 3: out = y @ w_out^T (fp32 out) ---------------------------
__global__ __launch_bounds__(256) void k_out(const unsigned short* __restrict__ yg,
                                             const float* __restrict__ wout,
                                             float* __restrict__ out) {
  __shared__ unsigned short As[64][200];
  __shared__ unsigned short Bs[64][200];
  const int m0 = blockIdx.x * 64;
  const int n0 = blockIdx.y * 64;
  const int tid = threadIdx.x;

#pragma unroll
  for (int it = 0; it < 6; ++it) {
    int f = tid + it * 256;
    int row = f / 24, c8 = (f % 24) * 8;
    *reinterpret_cast<uint4*>(&As[row][c8]) =
        *reinterpret_cast<const uint4*>(&yg[(size_t)(m0 + row) * Cn + c8]);
  }
#pragma unroll
  for (int it = 0; it < 12; ++it) {
    int f = tid + it * 256;
    int row = f / 48, c4 = (f % 48) * 4;
    float4 vb = *reinterpret_cast<const float4*>(&wout[(size_t)(n0 + row) * Cn + c4]);
    ushort4 ub; ub.x = f2bf(vb.x); ub.y = f2bf(vb.y); ub.z = f2bf(vb.z); ub.w = f2bf(vb.w);
    *reinterpret_cast<ushort4*>(&Bs[row][c4]) = ub;
  }
  __syncthreads();

  const int wv = tid >> 6, lane = tid & 63, llo = lane & 15, lhi = lane >> 4;
  const int wm = (wv >> 1) * 32, wn = (wv & 1) * 32;
  f32x4 acc[2][2] = {};
#pragma unroll
  for (int ks = 0; ks < 6; ++ks) {
    u16x8 a[2], b[2];
#pragma unroll
    for (int i = 0; i < 2; ++i)
      a[i] = *reinterpret_cast<const u16x8*>(&As[wm + 16 * i + llo][ks * 32 + lhi * 8]);
#pragma unroll
    for (int j = 0; j < 2; ++j)
      b[j] = *reinterpret_cast<const u16x8*>(&Bs[wn + 16 * j + llo][ks * 32 + lhi * 8]);
#pragma unroll
    for (int i = 0; i < 2; ++i)
#pragma unroll
      for (int j = 0; j < 2; ++j)
        acc[i][j] = mfma16x16x32(a[i], b[j], acc[i][j]);
  }
#pragma unroll
  for (int i = 0; i < 2; ++i)
#pragma unroll
    for (int j = 0; j < 2; ++j)
#pragma unroll
      for (int r = 0; r < 4; ++r) {
        int mg = m0 + wm + 16 * i + lhi * 4 + r;
        int ng = n0 + wn + 16 * j + llo;
        out[(size_t)mg * Cn + ng] = acc[i][j][r];
      }
}

extern "C" void kernel_launch(void* const* d_in, const int* in_sizes, int n_in,
                              void* d_out, int out_size, void* d_ws, size_t ws_size,
                              hipStream_t stream) {
  const float* x    = (const float*)d_in[0];
  const float* wqkv = (const float*)d_in[1];
  const float* wout = (const float*)d_in[2];
  float* out = (float*)d_out;

  const size_t NE = (size_t)Mn * Cn;        // 12,582,912 elements per tensor
  unsigned short* q = (unsigned short*)d_ws;
  unsigned short* k = q + NE;
  unsigned short* v = k + NE;
  unsigned short* y = v + NE;               // total 4*NE*2B = 100.7 MB of ws

  k_qkv<<<dim3(Mn / 64, (3 * Cn) / 64), 256, 0, stream>>>(x, wqkv, q, k, v);
  k_attn<<<dim3(Bn * Hn), 256, 0, stream>>>(q, k, v, y);
  k_out<<<dim3(Mn / 64, Cn / 64), 256, 0, stream>>>(y, wout, out);
}

// Round 3
// 105.637 us; speedup vs baseline: 1.5865x; 1.2469x over previous
//
#include <hip/hip_runtime.h>

// CausalSelfAttention: B=256 T=256 C=192 H=6 D=32, fp32 in/out, bf16 MFMA internal.
// k_qkv: row-owning GEMM, A direct-from-global-regs, W frag-linear LDS dbuf.
// k_attn: swapped-QK^T flash attention, in-register softmax.
// k_out: row-owning GEMM, A direct (bf16 y), W_out frag-linear LDS.

using f32x4  = __attribute__((ext_vector_type(4))) float;
using bf16x8 = __attribute__((ext_vector_type(8))) __bf16;
using u16x8  = __attribute__((ext_vector_type(8))) unsigned short;
using i32x4  = __attribute__((ext_vector_type(4))) int;

constexpr int Bn = 256;
constexpr int Tn = 256;
constexpr int Cn = 192;
constexpr int Hn = 6;
constexpr int Dn = 32;
constexpr int Mn = Bn * Tn;                 // 65536 tokens
constexpr float QSCALE = 0.2550533f;        // log2(e)/sqrt(32)

__device__ __forceinline__ unsigned short f2bf(float f) {
  unsigned int u = __builtin_bit_cast(unsigned int, f);
  u += 0x7fffu + ((u >> 16) & 1u);          // RNE
  return (unsigned short)(u >> 16);
}

__device__ __forceinline__ unsigned int cvtpk(float lo, float hi) {
  unsigned int r;
  asm("v_cvt_pk_bf16_f32 %0, %1, %2" : "=v"(r) : "v"(lo), "v"(hi));
  return r;
}

__device__ __forceinline__ u16x8 pack8(float4 a, float4 b, float s) {
  uint4 w;
  w.x = cvtpk(a.x * s, a.y * s);
  w.y = cvtpk(a.z * s, a.w * s);
  w.z = cvtpk(b.x * s, b.y * s);
  w.w = cvtpk(b.z * s, b.w * s);
  return __builtin_bit_cast(u16x8, w);
}

__device__ __forceinline__ f32x4 mfma16x16x32(u16x8 a, u16x8 b, f32x4 c) {
  return __builtin_amdgcn_mfma_f32_16x16x32_bf16(
      __builtin_bit_cast(bf16x8, a), __builtin_bit_cast(bf16x8, b), c, 0, 0, 0);
}

// ---------------- kernel 1: qkv = x @ w_qkv^T -> bf16 [B,H,T,D] --------------------
// 512 blocks x 4 waves; wave owns rows m0+32w..+31, all 576 cols via 9 n-tiles.
// A (x rows) loaded once to regs; W tile staged frag-linear in LDS, double-buffered.
__global__ __launch_bounds__(256, 2) void k_qkv(const float* __restrict__ x,
                                                const float* __restrict__ wqkv,
                                                unsigned short* __restrict__ qg,
                                                unsigned short* __restrict__ kg,
                                                unsigned short* __restrict__ vg) {
  __shared__ u16x8 Bsf[2][1536];            // [buf][(j*6+ks)*64+lane], 2 x 24 KiB
  const int tid = threadIdx.x;
  const int m0 = blockIdx.x * 128;
  const int w = tid >> 6, lane = tid & 63, llo = lane & 15, lhi = lane >> 4;

  // A-fragments: af[ks][i] = x[m0+32w+16i+llo][ks*32+lhi*8 ..+7], fp32->bf16 once
  u16x8 af[6][2];
#pragma unroll
  for (int i = 0; i < 2; ++i) {
    const float* xr = x + (size_t)(m0 + 32 * w + 16 * i + llo) * Cn + lhi * 8;
#pragma unroll
    for (int ks = 0; ks < 6; ++ks) {
      float4 a0 = *reinterpret_cast<const float4*>(xr + ks * 32);
      float4 a1 = *reinterpret_cast<const float4*>(xr + ks * 32 + 4);
      af[ks][i] = pack8(a0, a1, 1.0f);
    }
  }

  // stage tile nt=0 (q section -> QSCALE)
  {
    const int n0 = 0;
#pragma unroll
    for (int it = 0; it < 6; ++it) {
      int p = tid + it * 256;
      int j = p / 384, rem = p - j * 384;
      int ks = rem >> 6, l2 = rem & 63;
      int row = j * 16 + (l2 & 15), col = ks * 32 + ((l2 >> 4) << 3);
      const float* wp = wqkv + (size_t)(n0 + row) * Cn + col;
      float4 a0 = *reinterpret_cast<const float4*>(wp);
      float4 a1 = *reinterpret_cast<const float4*>(wp + 4);
      Bsf[0][p] = pack8(a0, a1, QSCALE);
    }
  }
  __syncthreads();

  for (int nt = 0; nt < 9; ++nt) {
    const int cur = nt & 1;
    // prefetch next W tile into regs
    float4 wr[6][2];
    if (nt < 8) {
      const int n0 = (nt + 1) * 64;
#pragma unroll
      for (int it = 0; it < 6; ++it) {
        int p = tid + it * 256;
        int j = p / 384, rem = p - j * 384;
        int ks = rem >> 6, l2 = rem & 63;
        int row = j * 16 + (l2 & 15), col = ks * 32 + ((l2 >> 4) << 3);
        const float* wp = wqkv + (size_t)(n0 + row) * Cn + col;
        wr[it][0] = *reinterpret_cast<const float4*>(wp);
        wr[it][1] = *reinterpret_cast<const float4*>(wp + 4);
      }
    }
    // compute 32x64 for this n-tile
    f32x4 acc[2][4] = {};
#pragma unroll
    for (int j = 0; j < 4; ++j) {
      u16x8 bb[6];
#pragma unroll
      for (int ks = 0; ks < 6; ++ks)
        bb[ks] = Bsf[cur][(j * 6 + ks) * 64 + lane];
#pragma unroll
      for (int ks = 0; ks < 6; ++ks)
#pragma unroll
        for (int i = 0; i < 2; ++i)
          acc[i][j] = mfma16x16x32(af[ks][i], bb[ks], acc[i][j]);
    }
    // write prefetched tile to other buffer
    if (nt < 8) {
      const float sc = (nt + 1 < 3) ? QSCALE : 1.0f;
#pragma unroll
      for (int it = 0; it < 6; ++it) {
        int p = tid + it * 256;
        Bsf[cur ^ 1][p] = pack8(wr[it][0], wr[it][1], sc);
      }
    }
    // epilogue: scatter to q/k/v bf16 [B,H,T,D]
    const int sidx = nt / 3;                 // 0=q 1=k 2=v
    unsigned short* dst = (sidx == 0) ? qg : (sidx == 1) ? kg : vg;
    const int nbase = (nt - sidx * 3) * 64;
#pragma unroll
    for (int i = 0; i < 2; ++i)
#pragma unroll
      for (int j = 0; j < 4; ++j)
#pragma unroll
        for (int r = 0; r < 4; ++r) {
          int mg = m0 + 32 * w + 16 * i + lhi * 4 + r;
          int nn = nbase + 16 * j + llo;
          int h = nn >> 5, d = nn & 31;
          int bb_ = mg >> 8, t = mg & 255;
          dst[(size_t)(bb_ * Hn + h) * (Tn * Dn) + t * Dn + d] = f2bf(acc[i][j][r]);
        }
    if (nt < 8) __syncthreads();
  }
}

// ---------------- kernel 2: flash attention per (b,h), causal, swapped-QK^T --------
__global__ __launch_bounds__(256, 3) void k_attn(const unsigned short* __restrict__ qg,
                                                 const unsigned short* __restrict__ kg,
                                                 const unsigned short* __restrict__ vg,
                                                 unsigned short* __restrict__ yg) {
  __shared__ unsigned short Ks[256][40];    // K rows, +8 pad
  __shared__ unsigned short Vt[32][264];    // V transposed [d][t], +8 pad
  const int bh = blockIdx.x;
  const int b = bh / Hn, h = bh - b * Hn;
  const size_t base = (size_t)bh * Tn * Dn;
  const int tid = threadIdx.x;

  { // stage K (row-major) and V (transposed): one row per thread
    int row = tid;
    const unsigned short* kp = kg + base + (size_t)row * Dn;
    *reinterpret_cast<uint4*>(&Ks[row][0])  = *reinterpret_cast<const uint4*>(kp + 0);
    *reinterpret_cast<uint4*>(&Ks[row][8])  = *reinterpret_cast<const uint4*>(kp + 8);
    *reinterpret_cast<uint4*>(&Ks[row][16]) = *reinterpret_cast<const uint4*>(kp + 16);
    *reinterpret_cast<uint4*>(&Ks[row][24]) = *reinterpret_cast<const uint4*>(kp + 24);
    const unsigned short* vp = vg + base + (size_t)row * Dn;
    u16x8 v0 = *reinterpret_cast<const u16x8*>(vp + 0);
    u16x8 v1 = *reinterpret_cast<const u16x8*>(vp + 8);
    u16x8 v2 = *reinterpret_cast<const u16x8*>(vp + 16);
    u16x8 v3 = *reinterpret_cast<const u16x8*>(vp + 24);
#pragma unroll
    for (int e = 0; e < 8; ++e) {
      Vt[e][row]      = v0[e];
      Vt[8 + e][row]  = v1[e];
      Vt[16 + e][row] = v2[e];
      Vt[24 + e][row] = v3[e];
    }
  }
  __syncthreads();

  const int w = tid >> 6, lane = tid & 63, llo = lane & 15, lhi = lane >> 4;
  u16x8 qf[4];
  const unsigned short* qp = qg + base + (size_t)w * 64 * Dn;
#pragma unroll
  for (int i = 0; i < 4; ++i)
    qf[i] = *reinterpret_cast<const u16x8*>(qp + (size_t)(16 * i + llo) * Dn + lhi * 8);

  f32x4 ot[2][4] = {};                      // O^T: [dj][qi]
  float m_[4], l_[4];
#pragma unroll
  for (int qi = 0; qi < 4; ++qi) { m_[qi] = -1e30f; l_[qi] = 0.f; }

  const int addr0 = (llo + ((lhi & 1) << 5)) << 2;
  const int addr1 = addr0 + 64;

  for (int kt = 0; kt <= w; ++kt) {
    u16x8 kf[4];
#pragma unroll
    for (int kj = 0; kj < 4; ++kj)
      kf[kj] = *reinterpret_cast<const u16x8*>(&Ks[kt * 64 + kj * 16 + llo][lhi * 8]);
    u16x8 vtf[2][2];
#pragma unroll
    for (int ks = 0; ks < 2; ++ks)
#pragma unroll
      for (int dj = 0; dj < 2; ++dj)
        vtf[ks][dj] = *reinterpret_cast<const u16x8*>(&Vt[16 * dj + llo][kt * 64 + ks * 32 + lhi * 8]);

#pragma unroll
    for (int qi = 0; qi < 4; ++qi) {
      f32x4 st[4];
#pragma unroll
      for (int kj = 0; kj < 4; ++kj)
        st[kj] = mfma16x16x32(kf[kj], qf[qi], f32x4{});
      if (kt == w) {
        int ql = 16 * qi + llo;
#pragma unroll
        for (int kj = 0; kj < 4; ++kj)
#pragma unroll
          for (int r = 0; r < 4; ++r) {
            int kl = kj * 16 + lhi * 4 + r;
            st[kj][r] = (kl > ql) ? -1e30f : st[kj][r];
          }
      }
      float x0 = fmaxf(fmaxf(st[0][0], st[0][1]), fmaxf(st[0][2], st[0][3]));
      float x1 = fmaxf(fmaxf(st[1][0], st[1][1]), fmaxf(st[1][2], st[1][3]));
      float x2 = fmaxf(fmaxf(st[2][0], st[2][1]), fmaxf(st[2][2], st[2][3]));
      float x3 = fmaxf(fmaxf(st[3][0], st[3][1]), fmaxf(st[3][2], st[3][3]));
      float mx = fmaxf(fmaxf(x0, x1), fmaxf(x2, x3));
      mx = fmaxf(mx, __shfl_xor(mx, 16));
      mx = fmaxf(mx, __shfl_xor(mx, 32));
      float mn = fmaxf(m_[qi], mx);
      float al = exp2f(m_[qi] - mn);
      float sum = 0.f;
#pragma unroll
      for (int kj = 0; kj < 4; ++kj) {
        float p0 = exp2f(st[kj][0] - mn);
        float p1 = exp2f(st[kj][1] - mn);
        float p2 = exp2f(st[kj][2] - mn);
        float p3 = exp2f(st[kj][3] - mn);
        st[kj][0] = p0; st[kj][1] = p1; st[kj][2] = p2; st[kj][3] = p3;
        sum += (p0 + p1) + (p2 + p3);
      }
      sum += __shfl_xor(sum, 16);
      sum += __shfl_xor(sum, 32);
      l_[qi] = l_[qi] * al + sum;
      m_[qi] = mn;
#pragma unroll
      for (int dj = 0; dj < 2; ++dj)
#pragma unroll
        for (int r = 0; r < 4; ++r)
          ot[dj][qi][r] *= al;

      int pk0[4], pk1[4];
#pragma unroll
      for (int kj = 0; kj < 4; ++kj) {
        pk0[kj] = (int)cvtpk(st[kj][0], st[kj][1]);
        pk1[kj] = (int)cvtpk(st[kj][2], st[kj][3]);
      }
#pragma unroll
      for (int ks = 0; ks < 2; ++ks) {
        i32x4 pw;
#pragma unroll
        for (int j = 0; j < 4; ++j) {
          int addr = (j < 2) ? addr0 : addr1;
          int slo = (j & 1) ? pk1[2 * ks]     : pk0[2 * ks];
          int shi = (j & 1) ? pk1[2 * ks + 1] : pk0[2 * ks + 1];
          int blo = __builtin_amdgcn_ds_bpermute(addr, slo);
          int bhi = __builtin_amdgcn_ds_bpermute(addr, shi);
          pw[j] = (lhi & 2) ? bhi : blo;
        }
        u16x8 pbv = __builtin_bit_cast(u16x8, pw);
#pragma unroll
        for (int dj = 0; dj < 2; ++dj)
          ot[dj][qi] = mfma16x16x32(vtf[ks][dj], pbv, ot[dj][qi]);
      }
    }
  }
#pragma unroll
  for (int qi = 0; qi < 4; ++qi) {
    float rl = 1.0f / l_[qi];
    int t = w * 64 + 16 * qi + llo;
    size_t yo = ((size_t)(b * Tn + t) * Hn + h) * Dn;
#pragma unroll
    for (int dj = 0; dj < 2; ++dj) {
      uint2 pkd;
      pkd.x = cvtpk(ot[dj][qi][0] * rl, ot[dj][qi][1] * rl);
      pkd.y = cvtpk(ot[dj][qi][2] * rl, ot[dj][qi][3] * rl);
      *reinterpret_cast<uint2*>(&yg[yo + 16 * dj + lhi * 4]) = pkd;
    }
  }
}

// ---------------- kernel 3: out = y @ w_out^T (fp32 out) ---------------------------
// 512 blocks x 4 waves; wave owns rows m0+32w..+31, all 192 cols in one pass.
__global__ __launch_bounds__(256, 2) void k_out(const unsigned short* __restrict__ yg,
                                                const float* __restrict__ wout,
                                                float* __restrict__ out) {
  __shared__ u16x8 Bof[4608];               // [(j*6+ks)*64+lane], 72 KiB
  const int tid = threadIdx.x;
  const int m0 = blockIdx.x * 128;
  const int w = tid >> 6, lane = tid & 63, llo = lane & 15, lhi = lane >> 4;

  // stage w_out frag-linear (once)
#pragma unroll
  for (int it = 0; it < 18; ++it) {
    int p = tid + it * 256;
    int j = p / 384, rem = p - j * 384;
    int ks = rem >> 6, l2 = rem & 63;
    int row = j * 16 + (l2 & 15), col = ks * 32 + ((l2 >> 4) << 3);
    const float* wp = wout + (size_t)row * Cn + col;
    float4 a0 = *reinterpret_cast<const float4*>(wp);
    float4 a1 = *reinterpret_cast<const float4*>(wp + 4);
    Bof[p] = pack8(a0, a1, 1.0f);
  }

  // A-fragments from y (bf16), direct
  u16x8 af[6][2];
#pragma unroll
  for (int i = 0; i < 2; ++i) {
    const unsigned short* yr = yg + (size_t)(m0 + 32 * w + 16 * i + llo) * Cn + lhi * 8;
#pragma unroll
    for (int ks = 0; ks < 6; ++ks)
      af[ks][i] = *reinterpret_cast<const u16x8*>(yr + ks * 32);
  }
  __syncthreads();

  f32x4 acc[2][12] = {};
#pragma unroll
  for (int j = 0; j < 12; ++j) {
    u16x8 bb[6];
#pragma unroll
    for (int ks = 0; ks < 6; ++ks)
      bb[ks] = Bof[(j * 6 + ks) * 64 + lane];
#pragma unroll
    for (int ks = 0; ks < 6; ++ks)
#pragma unroll
      for (int i = 0; i < 2; ++i)
        acc[i][j] = mfma16x16x32(af[ks][i], bb[ks], acc[i][j]);
  }
#pragma unroll
  for (int i = 0; i < 2; ++i)
#pragma unroll
    for (int j = 0; j < 12; ++j)
#pragma unroll
      for (int r = 0; r < 4; ++r) {
        int mg = m0 + 32 * w + 16 * i + lhi * 4 + r;
        int ng = 16 * j + llo;
        out[(size_t)mg * Cn + ng] = acc[i][j][r];
      }
}

extern "C" void kernel_launch(void* const* d_in, const int* in_sizes, int n_in,
                              void* d_out, int out_size, void* d_ws, size_t ws_size,
                              hipStream_t stream) {
  const float* x    = (const float*)d_in[0];
  const float* wqkv = (const float*)d_in[1];
  const float* wout = (const float*)d_in[2];
  float* out = (float*)d_out;

  const size_t NE = (size_t)Mn * Cn;
  unsigned short* q = (unsigned short*)d_ws;
  unsigned short* k = q + NE;
  unsigned short* v = k + NE;
  unsigned short* y = v + NE;               // 4*NE*2B = 100.7 MB of ws

  k_qkv<<<dim3(Mn / 128), 256, 0, stream>>>(x, wqkv, q, k, v);
  k_attn<<<dim3(Bn * Hn), 256, 0, stream>>>(q, k, v, y);
  k_out<<<dim3(Mn / 128), 256, 0, stream>>>(y, wout, out);
}